// Round 20
// baseline (61.795 us; speedup 1.0000x reference)
//
#include <hip/hip_runtime.h>
#include <math.h>

// Problem constants
#define BB    16                 // batch
#define HH    112                // input H == W
#define IMSZ  (HH*HH)            // 12544 floats per image plane
#define OO    256                // output channels
#define OHALF 128                // filters per block (o-split x2)
#define OHW   108                // output H == W
#define PLANE (OHW*OHW)          // 11664 pixels per (b,o) plane
#define MTOTAL (BB*PLANE)        // 186624 output pixels per o
#define MTILE 256                // pixels per block (16 M-frags, 2 per wave)
#define WRECB 144                // weight record bytes: hi[64] | lo[64] | pad[16]
#define WRECW 36                 // record size in u32 words
#define NXCD  8

typedef __attribute__((ext_vector_type(8))) short short8;   // 8 bf16 = 4 VGPR
typedef __attribute__((ext_vector_type(4))) float f32x4;

// round-to-nearest-even float -> bf16 (bit trick; inputs finite)
__device__ __forceinline__ unsigned short f2bf(float x) {
    unsigned u = __builtin_bit_cast(unsigned, x);
    return (unsigned short)((u + 0x7fffu + ((u >> 16) & 1u)) >> 16);
}
__device__ __forceinline__ float bf2f(unsigned short h) {
    unsigned u = ((unsigned)h) << 16;
    return __builtin_bit_cast(float, u);
}

// GEMM formulation: xw[p,o] = sum_k win[p][k] * w[o][k], K=25 padded to 32.
// bf16 hi/lo split, 3 MFMAs (hh, hl, lh) per image; d2 = x2 + w2 - 2*xw;
// (sqrt(a)+sqrt(b))^2 = a + b + 2*sqrt(a*b) -> 1 sqrt + 1 exp per output.
// R19: R12 structure (best measured, 50.3us) + NONTEMPORAL output stores.
// Output is write-once/never-read: regular stores allocate+dirty-evict every
// line of 186.6MB through the 32MB L2; nt policy streams past L2. This is
// the one store-path mechanism orthogonal to all falsified address-pattern
// theories (XCD swizzle R12, LDS-transpose R15, subtile runs R18).
__global__ __launch_bounds__(512)
void dist_rbf_mfma(const float* __restrict__ gx, const float* __restrict__ rx,
                   const float* __restrict__ gw, const float* __restrict__ rw,
                   const float* __restrict__ stdp, float* __restrict__ out)
{
    __shared__ __align__(16) unsigned wrec[2 * OHALF * WRECW];  // gray | rgb
    __shared__ float w2s[2 * OHALF];

    const int tid    = threadIdx.x;
    const int obase0 = blockIdx.y * OHALF;

    // ---- bijective XCD swizzle (m204) on the pixel-tile index ----
    const int nwg = gridDim.x;                 // 729 (not divisible by 8)
    const int hw  = blockIdx.x;
    const int xcd = hw % NXCD, idx = hw / NXCD;
    const int q = nwg / NXCD, r = nwg % NXCD;
    const int lb = (xcd < r ? xcd * (q + 1) : r * (q + 1) + (xcd - r) * q) + idx;

    // ---- stage weights: threads 0..255, thread t: image t>>7, filter t&127 ----
    if (tid < 2 * OHALF) {
        const int img = tid >> 7;
        const int o   = tid & (OHALF - 1);
        const float* wsrc = img ? rw : gw;
        unsigned* rec = wrec + img * OHALF * WRECW + o * WRECW;
        float v[32]; unsigned short h[32];
        float s = 0.f;
        #pragma unroll
        for (int i = 0; i < 32; i++) {
            float x = (i < 25) ? wsrc[(obase0 + o) * 25 + i] : 0.f;
            v[i] = x; s = fmaf(x, x, s); h[i] = f2bf(x);
        }
        w2s[img * OHALF + o] = s;
        #pragma unroll
        for (int wd = 0; wd < 16; wd++) {
            rec[wd] = (unsigned)h[2*wd] | ((unsigned)h[2*wd+1] << 16);
            unsigned short l0 = f2bf(v[2*wd]   - bf2f(h[2*wd]));
            unsigned short l1 = f2bf(v[2*wd+1] - bf2f(h[2*wd+1]));
            rec[16 + wd] = (unsigned)l0 | ((unsigned)l1 << 16);
        }
    }
    __syncthreads();

    const int lid  = tid & 63;
    const int wid  = tid >> 6;     // 8 waves
    const int mcol = lid & 15;     // A: pixel row; B: o col; C: col
    const int kgrp = lid >> 4;     // k-group: k in [kgrp*8, kgrp*8+8)
    const int k0   = kgrp * 8;

    const float sd   = stdp[0];
    const float kneg = -1.f / (2.f * sd * sd);

    const int pbase = lb * MTILE;

    // ---------------- build A fragments + x2 in registers ----------------
    short8 ah[2][2], al[2][2];     // [mf][img]
    float  x2v[2][2][4];           // [mf][img][r] : x2 of pixel row kgrp*4+r

    #pragma unroll
    for (int mf = 0; mf < 2; mf++) {
        const int p  = pbase + (wid * 2 + mf) * 16 + mcol;  // this lane's A row
        const int b  = p / PLANE;
        const int pp = p - b * PLANE;
        const int oh = pp / OHW;
        const int ow = pp - oh * OHW;
        const size_t ibase = (size_t)b * IMSZ + oh * HH + ow;
        #pragma unroll
        for (int img = 0; img < 2; img++) {
            const float* src = (img == 0 ? gx : rx) + ibase;
            float xs[8];
            float part = 0.f;
            #pragma unroll
            for (int j = 0; j < 8; j++) {
                int k = k0 + j;
                int r2 = k / 5, c2 = k - r2 * 5;
                float x = (k < 25) ? src[r2 * HH + c2] : 0.f;
                xs[j] = x; part = fmaf(x, x, part);
            }
            // reduce partial x2 across the 4 k-groups of this pixel
            part += __shfl_xor(part, 16);
            part += __shfl_xor(part, 32);
            // fetch x2 for the epilogue's C rows (pixels kgrp*4 + r)
            #pragma unroll
            for (int rr = 0; rr < 4; rr++)
                x2v[mf][img][rr] = __shfl(part, kgrp * 4 + rr);
            // bf16 hi/lo split
            short8 hi, lo;
            #pragma unroll
            for (int j = 0; j < 8; j++) {
                unsigned short hh = f2bf(xs[j]);
                hi[j] = (short)hh;
                lo[j] = (short)f2bf(xs[j] - bf2f(hh));
            }
            ah[mf][img] = hi; al[mf][img] = lo;
        }
    }

    // ---------------- main loop over 8 o-tiles of this half ----------------
    const char* wrecB = (const char*)wrec;
    #pragma unroll 2
    for (int ot = 0; ot < OHALF / 16; ot++) {
        const int olocal = ot * 16 + mcol;
        const char* recg = wrecB + (size_t)olocal * WRECB + kgrp * 16;
        const char* recr = recg + (size_t)OHALF * WRECB;
        short8 bhg = *(const short8*)recg;
        short8 blg = *(const short8*)(recg + 64);
        short8 bhr = *(const short8*)recr;
        short8 blr = *(const short8*)(recr + 64);
        const float w2g = w2s[olocal];
        const float w2r = w2s[OHALF + olocal];

        #pragma unroll
        for (int mf = 0; mf < 2; mf++) {
            f32x4 cg = {0.f, 0.f, 0.f, 0.f};
            f32x4 cr = {0.f, 0.f, 0.f, 0.f};
            cg = __builtin_amdgcn_mfma_f32_16x16x32_bf16(ah[mf][0], bhg, cg, 0, 0, 0);
            cg = __builtin_amdgcn_mfma_f32_16x16x32_bf16(ah[mf][0], blg, cg, 0, 0, 0);
            cg = __builtin_amdgcn_mfma_f32_16x16x32_bf16(al[mf][0], bhg, cg, 0, 0, 0);
            cr = __builtin_amdgcn_mfma_f32_16x16x32_bf16(ah[mf][1], bhr, cr, 0, 0, 0);
            cr = __builtin_amdgcn_mfma_f32_16x16x32_bf16(ah[mf][1], blr, cr, 0, 0, 0);
            cr = __builtin_amdgcn_mfma_f32_16x16x32_bf16(al[mf][1], bhr, cr, 0, 0, 0);

            // epilogue: 4 outputs = C rows kgrp*4+rr (pixels), col o
            f32x4 res;
            #pragma unroll
            for (int rr = 0; rr < 4; rr++) {
                float d2g = fmaf(-2.f, cg[rr], x2v[mf][0][rr] + w2g);
                float d2r = fmaf(-2.f, cr[rr], x2v[mf][1][rr] + w2r);
                d2g = fmaxf(d2g, 1e-12f);
                d2r = fmaxf(d2r, 1e-12f);
                // (sqrt(d2g)+sqrt(d2r))^2 = d2g + d2r + 2*sqrt(d2g*d2r)
                float d2 = fmaf(2.f, __builtin_amdgcn_sqrtf(d2g * d2r), d2g + d2r);
                res[rr] = __expf(kneg * d2);
            }
            // PLANE and prow0 are both multiples of 4 -> a 4-px group never
            // straddles a plane boundary; always one dwordx4.
            const int prow0 = pbase + (wid * 2 + mf) * 16 + kgrp * 4;
            const int b0  = prow0 / PLANE;
            const int pp0 = prow0 - b0 * PLANE;
            // NONTEMPORAL: stream past L2 (write-once output, never re-read)
            __builtin_nontemporal_store(
                res, (f32x4*)(out + ((size_t)(b0 * OO + obase0 + olocal)) * PLANE + pp0));
        }
    }
}

extern "C" void kernel_launch(void* const* d_in, const int* in_sizes, int n_in,
                              void* d_out, int out_size, void* d_ws, size_t ws_size,
                              hipStream_t stream) {
    const float* gx   = (const float*)d_in[0];
    const float* rx   = (const float*)d_in[1];
    const float* gw   = (const float*)d_in[2];
    const float* rw   = (const float*)d_in[3];
    const float* stdp = (const float*)d_in[4];
    float* out = (float*)d_out;

    dim3 grid(MTOTAL / MTILE, OO / OHALF, 1);   // 729 x 2
    dim3 block(512, 1, 1);
    dist_rbf_mfma<<<grid, block, 0, stream>>>(gx, rx, gw, rw, stdp, out);
}

// Round 21
// 46.656 us; speedup vs baseline: 1.3245x; 1.3245x over previous
//
#include <hip/hip_runtime.h>
#include <math.h>

// Problem constants
#define BB    16                 // batch
#define HH    112                // input H == W
#define IMSZ  (HH*HH)            // 12544 floats per image plane
#define OO    256                // output channels
#define OHW   108                // output H == W
#define PLANE (OHW*OHW)          // 11664 pixels per (b,o) plane
#define MTOTAL (BB*PLANE)        // 186624 output pixels per o
#define MTILE 256                // pixels per subtile (16 M-frags, 1 per wave)
#define KSUB  3                  // consecutive subtiles per block: 729/3 = 243
#define WRECB 144                // weight record bytes: hi[64] | lo[64] | pad[16]
#define WRECW 36                 // record size in u32 words
#define NXCD  8

typedef __attribute__((ext_vector_type(8))) short short8;   // 8 bf16 = 4 VGPR
typedef __attribute__((ext_vector_type(4))) float f32x4;

// round-to-nearest-even float -> bf16 (bit trick; inputs finite)
__device__ __forceinline__ unsigned short f2bf(float x) {
    unsigned u = __builtin_bit_cast(unsigned, x);
    return (unsigned short)((u + 0x7fffu + ((u >> 16) & 1u)) >> 16);
}
__device__ __forceinline__ float bf2f(unsigned short h) {
    unsigned u = ((unsigned)h) << 16;
    return __builtin_bit_cast(float, u);
}

// GEMM formulation: xw[p,o] = sum_k win[p][k] * w[o][k], K=25 padded to 32.
// bf16 hi/lo split, 3 MFMAs (hh, hl, lh) per image; d2 = x2 + w2 - 2*xw;
// (sqrt(a)+sqrt(b))^2 = a + b + 2*sqrt(a*b) -> 1 sqrt + 1 exp per output.
// R21: ONE BLOCK PER CU. 243 blocks (= 729 subtiles / KSUB=3), 1024 threads
// (16 waves, 4/SIMD), LDS 75.8KB forces single residency. Every prior round
// had >=2 co-resident blocks interleaving write streams through the same
// L1/TA/write queue; R18 normalized per-CU showed +23% write throughput from
// longer runs but wasted 29% of CUs (183 blocks). This keeps the run-length
// win (12KB/plane/block), solo residency, AND 95% CU coverage.
__global__ __launch_bounds__(1024)
void dist_rbf_mfma(const float* __restrict__ gx, const float* __restrict__ rx,
                   const float* __restrict__ gw, const float* __restrict__ rw,
                   const float* __restrict__ stdp, float* __restrict__ out)
{
    __shared__ __align__(16) unsigned wrec[2 * OO * WRECW];  // 73.7 KB
    __shared__ float w2s[2 * OO];

    const int tid = threadIdx.x;

    // ---- bijective XCD swizzle (m204) on the block index ----
    const int nwg = gridDim.x;                 // 243 (243 % 8 = 3)
    const int hw  = blockIdx.x;
    const int xcd = hw % NXCD, idx = hw / NXCD;
    const int q = nwg / NXCD, r = nwg % NXCD;
    const int lb = (xcd < r ? xcd * (q + 1) : r * (q + 1) + (xcd - r) * q) + idx;

    // ---- stage weights once: threads 0..511, thread t: image t>>8, filter t&255 ----
    if (tid < 2 * OO) {
        const int img = tid >> 8;
        const int o   = tid & 255;
        const float* wsrc = img ? rw : gw;
        unsigned* rec = wrec + img * OO * WRECW + o * WRECW;
        float v[32]; unsigned short h[32];
        float s = 0.f;
        #pragma unroll
        for (int i = 0; i < 32; i++) {
            float x = (i < 25) ? wsrc[o * 25 + i] : 0.f;
            v[i] = x; s = fmaf(x, x, s); h[i] = f2bf(x);
        }
        w2s[img * OO + o] = s;
        #pragma unroll
        for (int wd = 0; wd < 16; wd++) {
            rec[wd] = (unsigned)h[2*wd] | ((unsigned)h[2*wd+1] << 16);
            unsigned short l0 = f2bf(v[2*wd]   - bf2f(h[2*wd]));
            unsigned short l1 = f2bf(v[2*wd+1] - bf2f(h[2*wd+1]));
            rec[16 + wd] = (unsigned)l0 | ((unsigned)l1 << 16);
        }
    }
    __syncthreads();

    const int lid  = tid & 63;
    const int wid  = tid >> 6;     // 16 waves; wave owns M-frag `wid`
    const int mcol = lid & 15;     // A: pixel row; B: o col; C: col
    const int kgrp = lid >> 4;     // k-group: k in [kgrp*8, kgrp*8+8)
    const int k0   = kgrp * 8;

    const float sd   = stdp[0];
    const float kneg = -1.f / (2.f * sd * sd);
    const char* wrecB = (const char*)wrec;

    // ---------------- subtile loop: KSUB consecutive 256-px tiles ----------------
    for (int st = 0; st < KSUB; st++) {
        const int pbase = (lb * KSUB + st) * MTILE;   // always < MTOTAL (exact)

        // ---- build A fragment + x2 in registers for this subtile ----
        short8 ah[2], al[2];       // [img]
        float  x2v[2][4];          // [img][r] : x2 of pixel row kgrp*4+r

        {
            const int p  = pbase + wid * 16 + mcol;   // this lane's A row
            const int b  = p / PLANE;
            const int pp = p - b * PLANE;
            const int oh = pp / OHW;
            const int ow = pp - oh * OHW;
            const size_t ibase = (size_t)b * IMSZ + oh * HH + ow;
            #pragma unroll
            for (int img = 0; img < 2; img++) {
                const float* src = (img == 0 ? gx : rx) + ibase;
                float xs[8];
                float part = 0.f;
                #pragma unroll
                for (int j = 0; j < 8; j++) {
                    int k = k0 + j;
                    int r2 = k / 5, c2 = k - r2 * 5;
                    float x = (k < 25) ? src[r2 * HH + c2] : 0.f;
                    xs[j] = x; part = fmaf(x, x, part);
                }
                // reduce partial x2 across the 4 k-groups of this pixel
                part += __shfl_xor(part, 16);
                part += __shfl_xor(part, 32);
                // fetch x2 for the epilogue's C rows (pixels kgrp*4 + r)
                #pragma unroll
                for (int rr = 0; rr < 4; rr++)
                    x2v[img][rr] = __shfl(part, kgrp * 4 + rr);
                // bf16 hi/lo split
                short8 hi, lo;
                #pragma unroll
                for (int j = 0; j < 8; j++) {
                    unsigned short hh = f2bf(xs[j]);
                    hi[j] = (short)hh;
                    lo[j] = (short)f2bf(xs[j] - bf2f(hh));
                }
                ah[img] = hi; al[img] = lo;
            }
        }

        // ---- main loop over 16 o-tiles ----
        #pragma unroll 2
        for (int ot = 0; ot < 16; ot++) {
            const int o = ot * 16 + mcol;
            const char* recg = wrecB + (size_t)o * WRECB + kgrp * 16;
            const char* recr = recg + (size_t)OO * WRECB;
            short8 bhg = *(const short8*)recg;
            short8 blg = *(const short8*)(recg + 64);
            short8 bhr = *(const short8*)recr;
            short8 blr = *(const short8*)(recr + 64);
            const float w2g = w2s[o];
            const float w2r = w2s[OO + o];

            f32x4 cg = {0.f, 0.f, 0.f, 0.f};
            f32x4 cr = {0.f, 0.f, 0.f, 0.f};
            cg = __builtin_amdgcn_mfma_f32_16x16x32_bf16(ah[0], bhg, cg, 0, 0, 0);
            cg = __builtin_amdgcn_mfma_f32_16x16x32_bf16(ah[0], blg, cg, 0, 0, 0);
            cg = __builtin_amdgcn_mfma_f32_16x16x32_bf16(al[0], bhg, cg, 0, 0, 0);
            cr = __builtin_amdgcn_mfma_f32_16x16x32_bf16(ah[1], bhr, cr, 0, 0, 0);
            cr = __builtin_amdgcn_mfma_f32_16x16x32_bf16(ah[1], blr, cr, 0, 0, 0);
            cr = __builtin_amdgcn_mfma_f32_16x16x32_bf16(al[1], bhr, cr, 0, 0, 0);

            // epilogue: 4 outputs = C rows kgrp*4+rr (pixels), col o
            f32x4 res;
            #pragma unroll
            for (int rr = 0; rr < 4; rr++) {
                float d2g = fmaf(-2.f, cg[rr], x2v[0][rr] + w2g);
                float d2r = fmaf(-2.f, cr[rr], x2v[1][rr] + w2r);
                d2g = fmaxf(d2g, 1e-12f);
                d2r = fmaxf(d2r, 1e-12f);
                // (sqrt(d2g)+sqrt(d2r))^2 = d2g + d2r + 2*sqrt(d2g*d2r)
                float d2 = fmaf(2.f, __builtin_amdgcn_sqrtf(d2g * d2r), d2g + d2r);
                res[rr] = __expf(kneg * d2);
            }
            // PLANE and prow0 are both multiples of 4 -> a 4-px group never
            // straddles a plane boundary; always one dwordx4.
            const int prow0 = pbase + wid * 16 + kgrp * 4;
            const int b0  = prow0 / PLANE;
            const int pp0 = prow0 - b0 * PLANE;
            *(f32x4*)(out + ((size_t)(b0 * OO + o)) * PLANE + pp0) = res;
        }
    }
}

extern "C" void kernel_launch(void* const* d_in, const int* in_sizes, int n_in,
                              void* d_out, int out_size, void* d_ws, size_t ws_size,
                              hipStream_t stream) {
    const float* gx   = (const float*)d_in[0];
    const float* rx   = (const float*)d_in[1];
    const float* gw   = (const float*)d_in[2];
    const float* rw   = (const float*)d_in[3];
    const float* stdp = (const float*)d_in[4];
    float* out = (float*)d_out;

    dim3 grid(MTOTAL / (MTILE * KSUB), 1, 1);   // 243 blocks, exact
    dim3 block(1024, 1, 1);
    dist_rbf_mfma<<<grid, block, 0, stream>>>(gx, rx, gw, rw, stdp, out);
}